// Round 1
// baseline (1031.756 us; speedup 1.0000x reference)
//
#include <hip/hip_runtime.h>

// Problem constants (match reference setup_inputs)
#define B_N 64
#define H_N 512
#define W_N 512
#define T_N 100
#define TB  101        // T+1 buckets (bucket in [0,100])
#define R_N 8
#define NLAB 9         // labels 0..8 (0 = background)
#define BLOCKS_PER_IMG 16
#define PIX_PER_IMG (H_N * W_N)
#define PIX_PER_BLOCK (PIX_PER_IMG / BLOCKS_PER_IMG)   // 16384

// ---------------- K1: per-pixel bucket + segmented histogram ----------------
__global__ __launch_bounds__(256) void hist_kernel(
    const float* __restrict__ preds, const int* __restrict__ labels,
    const float* __restrict__ thr,
    int* __restrict__ region_hist,   // (B, R, TB)
    int* __restrict__ bg_hist)       // (B, TB)
{
    __shared__ float s_thr[T_N];
    __shared__ int whist[4][NLAB * TB];   // per-wave privatized, 4*909 ints

    const int tid  = threadIdx.x;
    const int wave = tid >> 6;

    for (int i = tid; i < 4 * NLAB * TB; i += 256) ((int*)whist)[i] = 0;
    if (tid < T_N) s_thr[tid] = thr[tid];
    __syncthreads();

    const int img   = blockIdx.x / BLOCKS_PER_IMG;
    const int chunk = blockIdx.x % BLOCKS_PER_IMG;
    const long base = (long)img * PIX_PER_IMG + (long)chunk * PIX_PER_BLOCK;
    const float4* p4 = (const float4*)(preds + base);
    const int4*   l4 = (const int4*)(labels + base);
    int* __restrict__ myh = whist[wave];

    const int iters = PIX_PER_BLOCK / (256 * 4);   // 16
    for (int it = 0; it < iters; ++it) {
        float4 pv = p4[it * 256 + tid];
        int4   lv = l4[it * 256 + tid];
        float ps[4] = {pv.x, pv.y, pv.z, pv.w};
        int   ls[4] = {lv.x, lv.y, lv.z, lv.w};
#pragma unroll
        for (int j = 0; j < 4; ++j) {
            float s = ps[j];
            // arithmetic guess for searchsorted(thr, s, 'right'); exact fixup below
            int k = (int)(s * (float)(T_N - 1)) + 1;
            k = max(0, min(T_N, k));
            while (k < T_N && s_thr[k] <= s) ++k;
            while (k > 0 && s_thr[k - 1] > s) --k;
            atomicAdd(&myh[ls[j] * TB + k], 1);
        }
    }
    __syncthreads();

    // merge wave copies, flush to global
    for (int i = tid; i < NLAB * TB; i += 256) {
        int v = whist[0][i] + whist[1][i] + whist[2][i] + whist[3][i];
        if (v) {
            int lab = i / TB;
            int t   = i - lab * TB;
            if (lab == 0)
                atomicAdd(&bg_hist[img * TB + t], v);
            else
                atomicAdd(&region_hist[(img * R_N + (lab - 1)) * TB + t], v);
        }
    }
}

// ---------------- K2: per-region cumsum -> sPRO, sum into spro_sum ----------------
__global__ __launch_bounds__(128) void region_kernel(
    const int* __restrict__ region_hist,   // (B, R, TB)
    float* __restrict__ spro_sum,          // (T)
    int* __restrict__ n_def)               // (1)
{
    __shared__ float spro_sh[R_N][T_N];
    __shared__ int validc[R_N];
    const int img = blockIdx.x;
    const int tid = threadIdx.x;

    if (tid < R_N) {
        const int* h = &region_hist[(img * R_N + tid) * TB];
        int area = 0;
        for (int t = 0; t < TB; ++t) area += h[t];
        float sat   = fmaxf((float)area, 1.0f);
        float valid = (area > 0) ? 1.0f : 0.0f;
        int csum = 0;
        for (int t = 0; t < T_N; ++t) {
            csum += h[t];
            float tp = (float)(area - csum);
            spro_sh[tid][t] = fminf(tp / sat, 1.0f) * valid;
        }
        validc[tid] = (area > 0) ? 1 : 0;
    }
    __syncthreads();

    if (tid < T_N) {
        float s = 0.0f;
        for (int r = 0; r < R_N; ++r) s += spro_sh[r][tid];
        atomicAdd(&spro_sum[tid], s);
    }
    if (tid == 0) {
        int v = 0;
        for (int r = 0; r < R_N; ++r) v += validc[r];
        atomicAdd(n_def, v);
    }
}

// ---------------- K3: fp/fpr, mean sPRO, stable argsort, trapezoid AUC ----------------
__global__ __launch_bounds__(128) void final_kernel(
    const int* __restrict__ bg_hist,      // (B, TB)
    const float* __restrict__ spro_sum,   // (T)
    const int* __restrict__ n_def,
    float* __restrict__ out)
{
    __shared__ int   bgh[TB];
    __shared__ float fpr_sh[T_N];
    __shared__ float ms_sh[T_N];
    const int tid = threadIdx.x;

    if (tid < TB) {
        int s = 0;
        for (int b = 0; b < B_N; ++b) s += bg_hist[b * TB + tid];
        bgh[tid] = s;
    }
    __syncthreads();

    if (tid == 0) {
        long bg_total = 0;
        for (int t = 0; t < TB; ++t) bg_total += bgh[t];
        float bgt = (float)bg_total;
        float nd  = fmaxf((float)(*n_def), 1.0f);
        int csum = 0;
        for (int t = 0; t < T_N; ++t) {
            csum += bgh[t];
            float fp = (float)(bg_total - csum);
            fpr_sh[t] = (bgt > 0.0f) ? fp / fmaxf(bgt, 1.0f) : 0.0f;
            ms_sh[t]  = spro_sum[t] / nd;
        }
        // stable ascending argsort (insertion sort; strict > keeps stability,
        // matching jnp.argsort tie semantics for the trapezoid pairing)
        int order[T_N];
        for (int i = 0; i < T_N; ++i) order[i] = i;
        for (int i = 1; i < T_N; ++i) {
            int oi = order[i];
            float v = fpr_sh[oi];
            int j = i - 1;
            while (j >= 0 && fpr_sh[order[j]] > v) { order[j + 1] = order[j]; --j; }
            order[j + 1] = oi;
        }
        double auc = 0.0;
        for (int i = 0; i + 1 < T_N; ++i) {
            double x0 = fpr_sh[order[i]],     x1 = fpr_sh[order[i + 1]];
            double y0 = ms_sh[order[i]],      y1 = ms_sh[order[i + 1]];
            auc += (x1 - x0) * (y0 + y1) * 0.5;
        }
        out[0] = (float)auc;
    }
}

extern "C" void kernel_launch(void* const* d_in, const int* in_sizes, int n_in,
                              void* d_out, int out_size, void* d_ws, size_t ws_size,
                              hipStream_t stream) {
    const float* preds  = (const float*)d_in[0];
    const float* thr    = (const float*)d_in[1];
    const int*   labels = (const int*)d_in[2];
    float* out = (float*)d_out;

    int*   region_hist = (int*)d_ws;                        // B*R*TB ints
    int*   bg_hist     = region_hist + B_N * R_N * TB;      // B*TB ints
    float* spro_sum    = (float*)(bg_hist + B_N * TB);      // T floats
    int*   n_def       = (int*)(spro_sum + T_N);            // 1 int

    size_t zbytes = sizeof(int) * (size_t)(B_N * R_N * TB + B_N * TB)
                  + sizeof(float) * T_N + sizeof(int);
    hipMemsetAsync(d_ws, 0, zbytes, stream);

    hist_kernel<<<B_N * BLOCKS_PER_IMG, 256, 0, stream>>>(preds, labels, thr,
                                                          region_hist, bg_hist);
    region_kernel<<<B_N, 128, 0, stream>>>(region_hist, spro_sum, n_def);
    final_kernel<<<1, 128, 0, stream>>>(bg_hist, spro_sum, n_def, out);
}

// Round 2
// 166.909 us; speedup vs baseline: 6.1815x; 6.1815x over previous
//
#include <hip/hip_runtime.h>

// Problem constants (match reference setup_inputs)
#define B_N 64
#define H_N 512
#define W_N 512
#define T_N 100
#define TB  101        // T+1 buckets (bucket in [0,100])
#define R_N 8
#define NLAB 9         // labels 0..8 (0 = background)
#define BLOCKS_PER_IMG 16
#define PIX_PER_IMG (H_N * W_N)
#define PIX_PER_BLOCK (PIX_PER_IMG / BLOCKS_PER_IMG)   // 16384

// ---------------- K1: per-pixel bucket + segmented histogram ----------------
__global__ __launch_bounds__(256) void hist_kernel(
    const float* __restrict__ preds, const int* __restrict__ labels,
    const float* __restrict__ thr,
    int* __restrict__ region_hist,   // (B, R, TB)
    int* __restrict__ bg_hist)       // (B, TB)
{
    __shared__ float s_thr[T_N];
    __shared__ int whist[4][NLAB * TB];   // per-wave privatized, 4*909 ints

    const int tid  = threadIdx.x;
    const int wave = tid >> 6;

    for (int i = tid; i < 4 * NLAB * TB; i += 256) ((int*)whist)[i] = 0;
    if (tid < T_N) s_thr[tid] = thr[tid];
    __syncthreads();

    const int img   = blockIdx.x / BLOCKS_PER_IMG;
    const int chunk = blockIdx.x % BLOCKS_PER_IMG;
    const long base = (long)img * PIX_PER_IMG + (long)chunk * PIX_PER_BLOCK;
    const float4* p4 = (const float4*)(preds + base);
    const int4*   l4 = (const int4*)(labels + base);
    int* __restrict__ myh = whist[wave];

    const int iters = PIX_PER_BLOCK / (256 * 4);   // 16
    for (int it = 0; it < iters; ++it) {
        float4 pv = p4[it * 256 + tid];
        int4   lv = l4[it * 256 + tid];
        float ps[4] = {pv.x, pv.y, pv.z, pv.w};
        int   ls[4] = {lv.x, lv.y, lv.z, lv.w};
#pragma unroll
        for (int j = 0; j < 4; ++j) {
            float s = ps[j];
            // arithmetic guess for searchsorted(thr, s, 'right'); exact fixup below
            int k = (int)(s * (float)(T_N - 1)) + 1;
            k = max(0, min(T_N, k));
            while (k < T_N && s_thr[k] <= s) ++k;
            while (k > 0 && s_thr[k - 1] > s) --k;
            atomicAdd(&myh[ls[j] * TB + k], 1);
        }
    }
    __syncthreads();

    // merge wave copies, flush to global
    for (int i = tid; i < NLAB * TB; i += 256) {
        int v = whist[0][i] + whist[1][i] + whist[2][i] + whist[3][i];
        if (v) {
            int lab = i / TB;
            int t   = i - lab * TB;
            if (lab == 0)
                atomicAdd(&bg_hist[img * TB + t], v);
            else
                atomicAdd(&region_hist[(img * R_N + (lab - 1)) * TB + t], v);
        }
    }
}

// ---------------- K2: per-region cumsum -> sPRO, sum into spro_sum ----------------
__global__ __launch_bounds__(128) void region_kernel(
    const int* __restrict__ region_hist,   // (B, R, TB)
    float* __restrict__ spro_sum,          // (T)
    int* __restrict__ n_def)               // (1)
{
    __shared__ float spro_sh[R_N][T_N];
    __shared__ int validc[R_N];
    const int img = blockIdx.x;
    const int tid = threadIdx.x;

    if (tid < R_N) {
        const int* h = &region_hist[(img * R_N + tid) * TB];
        int area = 0;
        for (int t = 0; t < TB; ++t) area += h[t];
        float sat   = fmaxf((float)area, 1.0f);
        float valid = (area > 0) ? 1.0f : 0.0f;
        int csum = 0;
        for (int t = 0; t < T_N; ++t) {
            csum += h[t];
            float tp = (float)(area - csum);
            spro_sh[tid][t] = fminf(tp / sat, 1.0f) * valid;
        }
        validc[tid] = (area > 0) ? 1 : 0;
    }
    __syncthreads();

    if (tid < T_N) {
        float s = 0.0f;
        for (int r = 0; r < R_N; ++r) s += spro_sh[r][tid];
        atomicAdd(&spro_sum[tid], s);
    }
    if (tid == 0) {
        int v = 0;
        for (int r = 0; r < R_N; ++r) v += validc[r];
        atomicAdd(n_def, v);
    }
}

// ---------------- K3: fp/fpr, mean sPRO, stable rank "argsort", trapezoid AUC ----------------
// All state lives in LDS; no dynamically-indexed private arrays (those spill to
// scratch and cost ~900 cyc/access — R1's final_kernel burned 880 us on that).
__global__ __launch_bounds__(128) void final_kernel(
    const int* __restrict__ bg_hist,      // (B, TB)
    const float* __restrict__ spro_sum,   // (T)
    const int* __restrict__ n_def,
    float* __restrict__ out)
{
    __shared__ int    bgh[TB];
    __shared__ float  fpr_sh[T_N];
    __shared__ float  ms_sh[T_N];
    __shared__ int    order[T_N];
    __shared__ double contrib[T_N];
    const int tid = threadIdx.x;

    if (tid < TB) {
        int s = 0;
        for (int b = 0; b < B_N; ++b) s += bg_hist[b * TB + tid];
        bgh[tid] = s;
    }
    __syncthreads();

    if (tid < T_N) {
        // fp[t] = #bg with bucket > t = suffix sum bgh[t+1..T]
        int fp_i = 0;
        for (int k = tid + 1; k < TB; ++k) fp_i += bgh[k];
        int tot = fp_i;
        for (int k = 0; k <= tid; ++k) tot += bgh[k];
        float bgt = (float)tot;
        float fp  = (float)fp_i;
        fpr_sh[tid] = (bgt > 0.0f) ? fp / fmaxf(bgt, 1.0f) : 0.0f;
        float nd = fmaxf((float)(*n_def), 1.0f);
        ms_sh[tid] = spro_sum[tid] / nd;
    }
    __syncthreads();

    if (tid < T_N) {
        // stable ascending argsort via exact rank (ties are bitwise-equal floats)
        float v = fpr_sh[tid];
        int r = 0;
        for (int j = 0; j < T_N; ++j) {
            float u = fpr_sh[j];
            r += (u < v) | ((u == v) & (j < tid));
        }
        order[r] = tid;
    }
    __syncthreads();

    if (tid < T_N - 1) {
        int o0 = order[tid], o1 = order[tid + 1];
        double x0 = fpr_sh[o0], x1 = fpr_sh[o1];
        double y0 = ms_sh[o0],  y1 = ms_sh[o1];
        contrib[tid] = (x1 - x0) * (y0 + y1) * 0.5;
    } else if (tid < T_N) {
        contrib[tid] = 0.0;
    }
    __syncthreads();

    if (tid == 0) {
        double s = 0.0;
        for (int i = 0; i < T_N - 1; ++i) s += contrib[i];
        out[0] = (float)s;
    }
}

extern "C" void kernel_launch(void* const* d_in, const int* in_sizes, int n_in,
                              void* d_out, int out_size, void* d_ws, size_t ws_size,
                              hipStream_t stream) {
    const float* preds  = (const float*)d_in[0];
    const float* thr    = (const float*)d_in[1];
    const int*   labels = (const int*)d_in[2];
    float* out = (float*)d_out;

    int*   region_hist = (int*)d_ws;                        // B*R*TB ints
    int*   bg_hist     = region_hist + B_N * R_N * TB;      // B*TB ints
    float* spro_sum    = (float*)(bg_hist + B_N * TB);      // T floats
    int*   n_def       = (int*)(spro_sum + T_N);            // 1 int

    size_t zbytes = sizeof(int) * (size_t)(B_N * R_N * TB + B_N * TB)
                  + sizeof(float) * T_N + sizeof(int);
    hipMemsetAsync(d_ws, 0, zbytes, stream);

    hist_kernel<<<B_N * BLOCKS_PER_IMG, 256, 0, stream>>>(preds, labels, thr,
                                                          region_hist, bg_hist);
    region_kernel<<<B_N, 128, 0, stream>>>(region_hist, spro_sum, n_def);
    final_kernel<<<1, 128, 0, stream>>>(bg_hist, spro_sum, n_def, out);
}